// Round 8
// baseline (226.427 us; speedup 1.0000x reference)
//
#include <hip/hip_runtime.h>
#include <math.h>

#define NB 2
#define NL 2048
#define NDIM 1024
#define NH 16
#define ND 64
#define NWS 256
#define NM (NB*NL)
// Q is pre-scaled by log2(e)/8 so attention uses exp2 directly
#define QSCALE 0.18033688011112042f

typedef __attribute__((ext_vector_type(8))) short short8;
typedef __attribute__((ext_vector_type(4))) float f32x4;
typedef unsigned short ushort_t;
typedef unsigned int uint_t;

#define MFMA16(a,b,acc) __builtin_amdgcn_mfma_f32_16x16x32_bf16((a),(b),(acc),0,0,0)

static __device__ __forceinline__ ushort_t f2bf(float x){
    uint_t u = __float_as_uint(x);
    uint_t r = (u + 0x7fff + ((u >> 16) & 1)) >> 16;   // RNE
    return (ushort_t)r;
}
static __device__ __forceinline__ float bf2f(ushort_t u){
    return __uint_as_float(((uint_t)u) << 16);
}
static __device__ __forceinline__ float fast_exp2(float x){
#if __has_builtin(__builtin_amdgcn_exp2f)
    return __builtin_amdgcn_exp2f(x);
#else
    return exp2f(x);
#endif
}

static __device__ __forceinline__ void async_load16(const void* g, void* l){
    __builtin_amdgcn_global_load_lds(
        (const __attribute__((address_space(1))) unsigned int*)g,
        (__attribute__((address_space(3))) unsigned int*)l, 16, 0, 0);
}

// ---------------- fused fp32 -> bf16 hi/lo split (x | Wqkv | Wproj) ----------------
// float4 ranges: x 1048576 | Wqkv 786432 | Wproj 262144  (total 2097152 = 8192*256)
__launch_bounds__(256)
__global__ void split_all(const float* __restrict__ x,  ushort_t* __restrict__ xh,  ushort_t* __restrict__ xl,
                          const float* __restrict__ wq, ushort_t* __restrict__ wqh, ushort_t* __restrict__ wql,
                          const float* __restrict__ wp, ushort_t* __restrict__ wph, ushort_t* __restrict__ wpl)
{
    int i = blockIdx.x*256 + threadIdx.x;   // float4 index
    const float* in; ushort_t *oh, *ol;
    if (i < 1048576)      { in = x;  oh = xh;  ol = xl;  }
    else if (i < 1835008) { in = wq; oh = wqh; ol = wql; i -= 1048576; }
    else                  { in = wp; oh = wph; ol = wpl; i -= 1835008; }
    const int e = i*4;
    const float4 v = *(const float4*)(in + e);
    ushort_t h0=f2bf(v.x), h1=f2bf(v.y), h2=f2bf(v.z), h3=f2bf(v.w);
    ushort4 h4; h4.x=h0; h4.y=h1; h4.z=h2; h4.w=h3;
    ushort4 l4;
    l4.x=f2bf(v.x - bf2f(h0)); l4.y=f2bf(v.y - bf2f(h1));
    l4.z=f2bf(v.z - bf2f(h2)); l4.w=f2bf(v.w - bf2f(h3));
    *(ushort4*)(oh + e) = h4;
    *(ushort4*)(ol + e) = l4;
}

// ---------------- rope cos/sin tables [j][l], j<32 ----------------
__launch_bounds__(256)
__global__ void rope_tab(float* __restrict__ tc, float* __restrict__ ts)
{
    const int idx = blockIdx.x*256 + threadIdx.x;   // 32*2048
    const int j = idx >> 11, l = idx & (NL-1);
    const float invf = 1.0f / powf(10000.0f, (float)j * (1.0f/32.0f));
    float s, c;
    sincosf((float)l * invf, &s, &c);
    tc[idx] = c; ts[idx] = s;
}

// ---------------- QKV GEMM: 128x128 tile, 2-slot dbuf (round-5/7 verified) ----------------
// 2-term hi/lo (ah*bh + al*bh), fused RoPE; Q (pre-scaled)/K bf16 -> [B,H,L,D],
// V -> transposed bf16 [B,H,D,L]. Pipeline: barrier -> stage(t+1) -> compute(t).
// LDS 50176 B (2x24K + guard, unions 36 KB V-bounce) -> 3 blocks/CU (grid = 3/CU).
__launch_bounds__(256, 3)
__global__ void gemm_qkv(const ushort_t* __restrict__ Ah, const ushort_t* __restrict__ Al,
                         const ushort_t* __restrict__ Bh,
                         const float* __restrict__ bias,
                         ushort_t* __restrict__ oQh, ushort_t* __restrict__ oKh,
                         ushort_t* __restrict__ oVth,
                         const float* __restrict__ tcos, const float* __restrict__ tsin)
{
    __shared__ __align__(16) char smem[50176];
    ushort_t* sA_h = (ushort_t*)smem;                    // 8 KB / slot
    ushort_t* sA_l = (ushort_t*)(smem + 8192);           // 8 KB / slot
    ushort_t* sB_h = (ushort_t*)(smem + 16384);          // 8 KB / slot
    ushort_t* sBounce = (ushort_t*)smem;                 // epilogue alias
    const int ebuf = 12288;                              // slot stride (elems)
    const int bbuf = 24576;                              // slot stride (bytes)

    const int tid  = threadIdx.x;
    const int wv   = tid >> 6, lane = tid & 63;
    const int quad = lane >> 4, l16 = lane & 15;
    const int m0 = blockIdx.y << 7, n0 = blockIdx.x << 7;
    const int wr = wv >> 1, wc = wv & 1;

    // staging: 0:A_h (8 passes) 1:A_l (8) 2:B_h rows0-63 (4) 3:B_h rows64-127 (4)
    const ushort_t* gsrc;
    ushort_t* lds_base;
    int rowb, npass;
    if (wv == 0)      { gsrc = Ah; lds_base = sA_h; rowb = m0; npass = 8; }
    else if (wv == 1) { gsrc = Al; lds_base = sA_l; rowb = m0; npass = 8; }
    else { gsrc = Bh; lds_base = sB_h + (wv-2)*64*32; rowb = n0 + (wv-2)*64; npass = 4; }
    const int rl = lane >> 2;
    const int cp = lane & 3;
    const int cg = cp ^ ((rl >> 1) & 3);
    const ushort_t* gptr = gsrc + (size_t)(rowb + rl)*NDIM + cg*8;

    f32x4 acc[4][4];
    #pragma unroll
    for (int i=0;i<4;++i)
        #pragma unroll
        for (int j=0;j<4;++j) acc[i][j] = (f32x4){0.f,0.f,0.f,0.f};

    const int swz = (l16 >> 1) & 3;
    const int ac_off = (wr*64 + l16)*32 + ((quad ^ swz) << 3);
    const int bc_off = (wc*64 + l16)*32 + ((quad ^ swz) << 3);

#define QSTAGE(BUF, KOFF) do { \
        const ushort_t* gp_ = gptr + (KOFF); \
        for (int p=0; p<npass; ++p) \
            async_load16(gp_ + (size_t)p*16*NDIM, (char*)lds_base + (BUF)*bbuf + p*1024); \
    } while(0)

#define QCOMP(BUF) do { \
        const int eo_ = (BUF)*ebuf; \
        short8 ah[4], al[4], bh[4]; \
        _Pragma("unroll") \
        for (int t=0;t<4;++t){ \
            ah[t] = *(const short8*)&sA_h[eo_ + t*512 + ac_off]; \
            al[t] = *(const short8*)&sA_l[eo_ + t*512 + ac_off]; \
            bh[t] = *(const short8*)&sB_h[eo_ + t*512 + bc_off]; \
        } \
        _Pragma("unroll") \
        for (int mt=0;mt<4;++mt) \
            _Pragma("unroll") \
            for (int nt=0;nt<4;++nt){ \
                f32x4 a_ = acc[mt][nt]; \
                a_ = MFMA16(ah[mt], bh[nt], a_); \
                a_ = MFMA16(al[mt], bh[nt], a_); \
                acc[mt][nt] = a_; \
            } \
    } while(0)

    QSTAGE(0, 0);
    for (int k0 = 0; k0 < NDIM; k0 += 64) {
        __syncthreads();                   // buf0 (k0) loads landed
        QSTAGE(1, k0 + 32);                // k0+32 <= 992 < NDIM always
        QCOMP(0);
        __syncthreads();                   // buf1 landed; buf0 free
        if (k0 + 64 < NDIM) QSTAGE(0, k0 + 64);
        QCOMP(1);
    }
#undef QSTAGE
#undef QCOMP

    const int colb = n0 + wc*64;          // 64-aligned -> single (sel, head)
    const int sel  = colb >> 10;          // 0:q 1:k 2:v
    const int head = (colb & 1023) >> 6;
    float bq[4];
    #pragma unroll
    for (int nt=0;nt<4;++nt) bq[nt] = bias[colb + nt*16 + l16];

    if (sel == 2) {
        // V -> transposed global [B,H,D,L] (bf16 only) via per-wave LDS bounce.
        // sBounce aliases the staging slots: barrier before overwrite.
        __syncthreads();
        const int bb = m0 >> 11;
        const int Lb = (m0 & (NL-1)) + wr*64;
        ushort_t* sT = sBounce + wv*(64*72);
        const size_t gb = ((size_t)(bb*NH + head)*ND)*NL + Lb;
        const int drow = lane >> 3, dcol = lane & 7;
        #pragma unroll
        for (int mt=0;mt<4;++mt)
            #pragma unroll
            for (int nt=0;nt<4;++nt)
                #pragma unroll
                for (int r=0;r<4;++r)
                    sT[(nt*16+l16)*72 + mt*16 + quad*4 + r] = f2bf(acc[mt][nt][r] + bq[nt]);
        #pragma unroll
        for (int dd=0; dd<8; ++dd){
            const int d = dd*8 + drow;
            const uint4 v = *(const uint4*)&sT[d*72 + dcol*8];
            *(uint4*)(oVth + gb + (size_t)d*NL + dcol*8) = v;
        }
    } else {
        ushort_t* dh = sel ? oKh : oQh;
        const float qs = sel ? 1.0f : QSCALE;
        #pragma unroll
        for (int mt=0;mt<4;++mt)
            #pragma unroll
            for (int r=0;r<4;++r){
                const int m = m0 + wr*64 + mt*16 + quad*4 + r;
                const int bb = m >> 11, l = m & (NL-1);
                const size_t ro = ((size_t)((bb*NH + head)*NL + l)) << 6;
                #pragma unroll
                for (int ntp=0;ntp<2;++ntp){
                    const int j = ntp*16 + l16;
                    const float c = tcos[j*NL + l];
                    const float s = tsin[j*NL + l];
                    const float x1 = acc[mt][ntp  ][r] + bq[ntp];
                    const float x2 = acc[mt][ntp+2][r] + bq[ntp+2];
                    const int d1 = ntp*16 + l16;
                    dh[ro + d1]      = f2bf((x1*c - x2*s) * qs);
                    dh[ro + d1 + 32] = f2bf((x2*c + x1*s) * qs);
                }
            }
    }
}

// ---------------- proj GEMM: 128x128 tile, 3-slot counted-vmcnt, 1 block/CU ----------------
// 3-term hi/lo, fp32 row-major C. 48 MFMA : 16 ds_read_b128 per phase (3:1 ratio,
// 2x the per-barrier MFMA work of the 128x64 version). grid 8x32 = 256 = 1 block/CU
// (single pass); all latency hiding is the in-wave counted-vmcnt prefetch
// (3 phases ~900cy ahead, round-6-verified schedule). Every wave stages 8x1KB
// per slot -> wave-uniform vmcnt: steady 16, tail 8 -> 0.
// LDS 3 x 32 KB + guard = 99328 B. Same-n blocks land on one XCD (ids stride 8)
// so each Wp panel stays L2-resident.
__launch_bounds__(256, 1)
__global__ void gemm_proj(const ushort_t* __restrict__ Ah, const ushort_t* __restrict__ Al,
                          const ushort_t* __restrict__ Bh, const ushort_t* __restrict__ Bl,
                          const float* __restrict__ bias,
                          float* __restrict__ Cout)
{
    __shared__ __align__(16) char smem[99328];           // 3 x 32768 + 1024 pad
    ushort_t* sA_h = (ushort_t*)smem;                    // 8 KB / slot
    ushort_t* sA_l = (ushort_t*)(smem + 8192);           // 8 KB / slot
    ushort_t* sB_h = (ushort_t*)(smem + 16384);          // 8 KB / slot
    ushort_t* sB_l = (ushort_t*)(smem + 24576);          // 8 KB / slot
    const int ebuf = 16384;                              // slot stride (elems)
    const int bbuf = 32768;                              // slot stride (bytes)

    const int tid  = threadIdx.x;
    const int wv   = tid >> 6, lane = tid & 63;
    const int quad = lane >> 4, l16 = lane & 15;
    const int m0 = blockIdx.y << 7, n0 = blockIdx.x << 7;
    const int wr = wv >> 1, wc = wv & 1;

    // uniform staging: every wave 8 passes (A_h x2, A_l x2, B_h x2, B_l x2),
    // wave wv covers rows [32*wv, 32*wv+32) of each 128-row operand
    const int rl = lane >> 2;
    const int cp = lane & 3;
    const int cg = cp ^ ((rl >> 1) & 3);
    const ushort_t* pAh = Ah + (size_t)(m0 + 32*wv + rl)*NDIM + cg*8;
    const ushort_t* pAl = Al + (size_t)(m0 + 32*wv + rl)*NDIM + cg*8;
    const ushort_t* pBh = Bh + (size_t)(n0 + 32*wv + rl)*NDIM + cg*8;
    const ushort_t* pBl = Bl + (size_t)(n0 + 32*wv + rl)*NDIM + cg*8;
    char* dAh = smem         + wv*2048;                  // 2 passes: +0, +1024
    char* dAl = smem + 8192  + wv*2048;
    char* dBh = smem + 16384 + wv*2048;
    char* dBl = smem + 24576 + wv*2048;

    f32x4 acc[4][4];
    #pragma unroll
    for (int i=0;i<4;++i)
        #pragma unroll
        for (int j=0;j<4;++j) acc[i][j] = (f32x4){0.f,0.f,0.f,0.f};

    const int swz = (l16 >> 1) & 3;
    const int ac_off = (wr*64 + l16)*32 + ((quad ^ swz) << 3);
    const int bc_off = (wc*64 + l16)*32 + ((quad ^ swz) << 3);

#define PSTAGE(SLOT, KOFF) do { \
        const int so_ = (SLOT)*bbuf; \
        async_load16(pAh + (KOFF),           dAh + so_); \
        async_load16(pAh + 16*NDIM + (KOFF), dAh + so_ + 1024); \
        async_load16(pAl + (KOFF),           dAl + so_); \
        async_load16(pAl + 16*NDIM + (KOFF), dAl + so_ + 1024); \
        async_load16(pBh + (KOFF),           dBh + so_); \
        async_load16(pBh + 16*NDIM + (KOFF), dBh + so_ + 1024); \
        async_load16(pBl + (KOFF),           dBl + so_); \
        async_load16(pBl + 16*NDIM + (KOFF), dBl + so_ + 1024); \
    } while(0)

#define PCOMP(SLOT) do { \
        const int eo_ = (SLOT)*ebuf; \
        short8 ah[4], al[4], bh[4], bl[4]; \
        _Pragma("unroll") \
        for (int t=0;t<4;++t){ \
            ah[t] = *(const short8*)&sA_h[eo_ + t*512 + ac_off]; \
            al[t] = *(const short8*)&sA_l[eo_ + t*512 + ac_off]; \
            bh[t] = *(const short8*)&sB_h[eo_ + t*512 + bc_off]; \
            bl[t] = *(const short8*)&sB_l[eo_ + t*512 + bc_off]; \
        } \
        _Pragma("unroll") \
        for (int mt=0;mt<4;++mt) \
            _Pragma("unroll") \
            for (int nt=0;nt<4;++nt){ \
                f32x4 a_ = acc[mt][nt]; \
                a_ = MFMA16(ah[mt], bh[nt], a_); \
                a_ = MFMA16(al[mt], bh[nt], a_); \
                a_ = MFMA16(ah[mt], bl[nt], a_); \
                acc[mt][nt] = a_; \
            } \
    } while(0)

#define PPHASE(SLOT, K0, VN) do { \
        asm volatile("s_waitcnt vmcnt(" #VN ")" ::: "memory"); \
        __builtin_amdgcn_sched_barrier(0); \
        __builtin_amdgcn_s_barrier(); \
        __builtin_amdgcn_sched_barrier(0); \
        PCOMP(SLOT); \
        asm volatile("s_waitcnt lgkmcnt(0)" ::: "memory"); \
        __builtin_amdgcn_sched_barrier(0); \
        __builtin_amdgcn_s_barrier(); \
        __builtin_amdgcn_sched_barrier(0); \
        if ((K0) + 96 < NDIM) PSTAGE(SLOT, (K0) + 96); \
    } while(0)

    PSTAGE(0, 0); PSTAGE(1, 32); PSTAGE(2, 64);
    for (int k0 = 0; k0 < 960; k0 += 96) {      // phases k = 0..928
        PPHASE(0, k0,      16);
        PPHASE(1, k0 + 32, 16);
        PPHASE(2, k0 + 64, 16);
    }
    PPHASE(0, 960, 8);                           // only k=992's 8 loads remain
    PPHASE(1, 992, 0);                           // full drain
#undef PSTAGE
#undef PCOMP
#undef PPHASE

    const int colb = n0 + wc*64;
    float bq[4];
    #pragma unroll
    for (int nt=0;nt<4;++nt) bq[nt] = bias[colb + nt*16 + l16];
    #pragma unroll
    for (int mt=0;mt<4;++mt)
        #pragma unroll
        for (int r=0;r<4;++r){
            const int m = m0 + wr*64 + mt*16 + quad*4 + r;
            float* orow = Cout + (size_t)m*NDIM + colb;
            #pragma unroll
            for (int nt=0;nt<4;++nt)
                orow[nt*16 + l16] = acc[mt][nt][r] + bq[nt];
        }
}

// ---------------- MFMA flash attention v2: cooperative LDS pipeline ----------------
// block = 256 thr = 4 waves; each wave owns 16 queries end-to-end over ALL keys
// (no cross-wave combine). K and V^T tiles (64 keys) staged cooperatively into
// double-buffered LDS via global_load_lds (pre-swizzled source, XOR-swizzled reads).
// Pipeline: barrier -> issue stage(t+1) -> compute(t). Softmax denominator via
// MFMA against an all-ones B fragment (ls lands in epilogue row layout directly).
__launch_bounds__(256, 4)
__global__ void attn_mfma(const ushort_t* __restrict__ Qh,
                          const ushort_t* __restrict__ Kh,
                          const ushort_t* __restrict__ Vth,
                          ushort_t* __restrict__ AOh, ushort_t* __restrict__ AOl,
                          const int* __restrict__ isg)
{
    // LDS map (bytes): [0,8K) K buf0 | [8K,16K) K buf1 | [16K,24K) V buf0
    //                  [24K,32K) V buf1 | [32K,40K) per-wave P tiles (2KB each)
    __shared__ __align__(16) char smem[40960];

    const int tid  = threadIdx.x;
    const int wv   = tid >> 6, lane = tid & 63;
    const int quad = lane >> 4, l16 = lane & 15;
    const int bh = blockIdx.x & 31, qt = blockIdx.x >> 5;   // XCD-local bh
    const int q0w = qt*64 + wv*16;

    // ---- Q B-frags (n=query on l16, k=d); Q pre-scaled by log2e/8 ----
    short8 bq0, bq1;
    {
        const size_t rb = (((size_t)bh*NL + q0w) << 6) + (size_t)(l16 << 6) + quad*8;
        bq0 = *(const short8*)(Qh + rb);
        bq1 = *(const short8*)(Qh + rb + 32);
    }
    short8 ones;
    #pragma unroll
    for (int j=0;j<8;++j) ones[j] = (short)0x3F80;   // bf16 1.0

    f32x4 o[4];
    #pragma unroll
    for (int dnt=0; dnt<4; ++dnt) o[dnt] = (f32x4){0.f,0.f,0.f,0.f};
    f32x4 lsacc = (f32x4){0.f,0.f,0.f,0.f};

    const int gflag = isg[0];
    int klo, khi;
    if (gflag) { klo = 0; khi = NL; }
    else       { klo = (qt >> 2)*NWS; khi = klo + NWS; }

    // ---- LDS read/write lane constants (XOR swizzle: byte ^= (row&7)<<4) ----
    const int swz4 = (l16 & 7) << 4;
    const int KC0 = l16*128 + (( quad*16      ) ^ swz4);   // c=0 frag (k 0-31)
    const int KC1 = l16*128 + (( quad*16 + 64 ) ^ swz4);   // c=1 frag (k 32-63)
    const int sPb = 32768 + wv*2048;
    int PW[4];
    #pragma unroll
    for (int knt=0; knt<4; ++knt)
        PW[knt] = sPb + l16*128 + ((knt*32 + quad*8) ^ swz4);
    const int PR0 = sPb + KC0;
    const int PR1 = sPb + KC1;

    // ---- staging pointers: pre-swizzled global source, linear LDS dest ----
    // wave wv stages rows [wv*16, wv*16+16) of both the K tile and the V^T tile
    const int r8  = lane >> 3;
    const int c8s = (lane & 7) ^ r8;                       // swizzled 16B slot
    const ushort_t* Kp = Kh + (((size_t)bh*NL) << 6)
                       + (size_t)(klo + wv*16 + r8)*64 + c8s*8;
    const ushort_t* Vp = Vth + (size_t)bh*ND*NL
                       + (size_t)(wv*16 + r8)*NL + klo + c8s*8;
    const int kdst = wv*2048;            // + BUF*8192
    const int vdst = 16384 + wv*2048;    // + BUF*8192

#define STAGE(BUF) do { \
        async_load16(Kp,          smem + (BUF)*8192 + kdst); \
        async_load16(Kp + 512,    smem + (BUF)*8192 + kdst + 1024); \
        async_load16(Vp,          smem + (BUF)*8192 + vdst); \
        async_load16(Vp + 8*NL,   smem + (BUF)*8192 + vdst + 1024); \
        Kp += 64*64; Vp += 64; } while (0)

#define TILE(BUF) do { \
        const char* kb_ = smem + (BUF)*8192; \
        const char* vb_ = smem + 16384 + (BUF)*8192; \
        f32x4 s_[4]; \
        _Pragma("unroll") \
        for (int knt=0; knt<4; ++knt) { \
            const short8 a0 = *(const short8*)(kb_ + knt*2048 + KC0); \
            const short8 a1 = *(const short8*)(kb_ + knt*2048 + KC1); \
            f32x4 t = (f32x4){0.f,0.f,0.f,0.f}; \
            t = MFMA16(a0, bq0, t); \
            t = MFMA16(a1, bq1, t); \
            s_[knt] = t; \
        } \
        _Pragma("unroll") \
        for (int knt=0; knt<4; ++knt) { \
            const uint_t u0 = __float_as_uint(fast_exp2(s_[knt][0])); \
            const uint_t u1 = __float_as_uint(fast_exp2(s_[knt][1])); \
            const uint_t u2 = __float_as_uint(fast_exp2(s_[knt][2])); \
            const uint_t u3 = __float_as_uint(fast_exp2(s_[knt][3])); \
            uint2 pk_; \
            pk_.x = __builtin_amdgcn_perm(u1, u0, 0x07060302u); \
            pk_.y = __builtin_amdgcn_perm(u3, u2, 0x07060302u); \
            *(uint2*)(smem + PW[knt]) = pk_; \
        } \
        const short8 fp0 = *(const short8*)(smem + PR0); \
        const short8 fp1 = *(const short8*)(smem + PR1); \
        lsacc = MFMA16(fp0, ones, lsacc); \
        lsacc = MFMA16(fp1, ones, lsacc); \
        _Pragma("unroll") \
        for (int dnt=0; dnt<4; ++dnt) { \
            const short8 v0 = *(const short8*)(vb_ + dnt*2048 + KC0); \
            const short8 v1 = *(const short8*)(vb_ + dnt*2048 + KC1); \
            f32x4 t = o[dnt]; \
            t = MFMA16(fp0, v0, t); \
            t = MFMA16(fp1, v1, t); \
            o[dnt] = t; \
        } } while (0)

    STAGE(0);
    for (int kt = klo; kt < khi; kt += 128) {
        __syncthreads();                       // drains vmcnt: tile kt landed
        if (kt + 64 < khi) STAGE(1);
        TILE(0);
        __syncthreads();                       // tile kt+64 landed
        if (kt + 128 < khi) STAGE(0);
        TILE(1);
    }
#undef STAGE
#undef TILE

    // ---- epilogue: O rows = quad*4+r; lsacc already in matching layout ----
    const int bb = bh >> 4, hh = bh & 15;
    #pragma unroll
    for (int r=0; r<4; ++r) {
        const float inv = 1.0f / lsacc[r];
        const int row = q0w + quad*4 + r;
        const size_t ob = (((size_t)(bb*NL + row)) << 10) + (hh << 6);
        #pragma unroll
        for (int dnt=0; dnt<4; ++dnt) {
            const float val = o[dnt][r] * inv;
            const ushort_t h = f2bf(val);
            AOh[ob + dnt*16 + l16] = h;
            AOl[ob + dnt*16 + l16] = f2bf(val - bf2f(h));
        }
    }
}

extern "C" void kernel_launch(void* const* d_in, const int* in_sizes, int n_in,
                              void* d_out, int out_size, void* d_ws, size_t ws_size,
                              hipStream_t stream)
{
    const float* x     = (const float*)d_in[0];
    const float* Wqkv  = (const float*)d_in[1];
    const float* bqkv  = (const float*)d_in[2];
    const float* Wproj = (const float*)d_in[3];
    const float* bproj = (const float*)d_in[4];
    const int*   isg   = (const int*)d_in[5];
    float* out = (float*)d_out;
    char* base = (char*)d_ws;

    const size_t MB = 1024*1024;
    ushort_t* Qh  = (ushort_t*)(base);
    ushort_t* Kh  = (ushort_t*)(base + 16*MB);
    ushort_t* Vth = (ushort_t*)(base + 32*MB);
    ushort_t* xh  = (ushort_t*)(base + 48*MB);
    ushort_t* xl  = (ushort_t*)(base + 56*MB);
    ushort_t* AOh = xh;                       // alias: xh dead after gemm1
    ushort_t* AOl = xl;
    ushort_t* Wqh = (ushort_t*)(base + 64*MB);
    ushort_t* Wql = (ushort_t*)(base + 64*MB + 6291456);
    ushort_t* Wph = (ushort_t*)(base + 76*MB);
    ushort_t* Wpl = (ushort_t*)(base + 76*MB + 2097152);
    float*    tcs = (float*)(base + 80*MB);          // 32*2048 f32
    float*    tsn = (float*)(base + 80*MB + 262144);

    split_all<<<8192, 256, 0, stream>>>(x, xh, xl, Wqkv, Wqh, Wql, Wproj, Wph, Wpl);
    rope_tab<<<256, 256, 0, stream>>>(tcs, tsn);

    gemm_qkv<<<dim3(3*NDIM/128, NM/128), 256, 0, stream>>>(
        xh, xl, Wqh, bqkv, Qh, Kh, Vth, tcs, tsn);

    attn_mfma<<<NB*NH*(NL/64), 256, 0, stream>>>(
        Qh, Kh, Vth, AOh, AOl, isg);

    gemm_proj<<<dim3(NDIM/128, NM/128), 256, 0, stream>>>(
        AOh, AOl, Wph, Wpl, bproj, out);
}

// Round 9
// 212.667 us; speedup vs baseline: 1.0647x; 1.0647x over previous
//
#include <hip/hip_runtime.h>
#include <math.h>

#define NB 2
#define NL 2048
#define NDIM 1024
#define NH 16
#define ND 64
#define NWS 256
#define NM (NB*NL)
// Q is pre-scaled by log2(e)/8 so attention uses exp2 directly
#define QSCALE 0.18033688011112042f

typedef __attribute__((ext_vector_type(8))) short short8;
typedef __attribute__((ext_vector_type(4))) float f32x4;
typedef unsigned short ushort_t;
typedef unsigned int uint_t;

#define MFMA16(a,b,acc) __builtin_amdgcn_mfma_f32_16x16x32_bf16((a),(b),(acc),0,0,0)

static __device__ __forceinline__ ushort_t f2bf(float x){
    uint_t u = __float_as_uint(x);
    uint_t r = (u + 0x7fff + ((u >> 16) & 1)) >> 16;   // RNE
    return (ushort_t)r;
}
static __device__ __forceinline__ float bf2f(ushort_t u){
    return __uint_as_float(((uint_t)u) << 16);
}
static __device__ __forceinline__ float fast_exp2(float x){
#if __has_builtin(__builtin_amdgcn_exp2f)
    return __builtin_amdgcn_exp2f(x);
#else
    return exp2f(x);
#endif
}

static __device__ __forceinline__ void async_load16(const void* g, void* l){
    __builtin_amdgcn_global_load_lds(
        (const __attribute__((address_space(1))) unsigned int*)g,
        (__attribute__((address_space(3))) unsigned int*)l, 16, 0, 0);
}

// ---------------- fused fp32 -> bf16 hi/lo split (x | Wqkv | Wproj) ----------------
// float4 ranges: x 1048576 | Wqkv 786432 | Wproj 262144  (total 2097152 = 8192*256)
__launch_bounds__(256)
__global__ void split_all(const float* __restrict__ x,  ushort_t* __restrict__ xh,  ushort_t* __restrict__ xl,
                          const float* __restrict__ wq, ushort_t* __restrict__ wqh, ushort_t* __restrict__ wql,
                          const float* __restrict__ wp, ushort_t* __restrict__ wph, ushort_t* __restrict__ wpl)
{
    int i = blockIdx.x*256 + threadIdx.x;   // float4 index
    const float* in; ushort_t *oh, *ol;
    if (i < 1048576)      { in = x;  oh = xh;  ol = xl;  }
    else if (i < 1835008) { in = wq; oh = wqh; ol = wql; i -= 1048576; }
    else                  { in = wp; oh = wph; ol = wpl; i -= 1835008; }
    const int e = i*4;
    const float4 v = *(const float4*)(in + e);
    ushort_t h0=f2bf(v.x), h1=f2bf(v.y), h2=f2bf(v.z), h3=f2bf(v.w);
    ushort4 h4; h4.x=h0; h4.y=h1; h4.z=h2; h4.w=h3;
    ushort4 l4;
    l4.x=f2bf(v.x - bf2f(h0)); l4.y=f2bf(v.y - bf2f(h1));
    l4.z=f2bf(v.z - bf2f(h2)); l4.w=f2bf(v.w - bf2f(h3));
    *(ushort4*)(oh + e) = h4;
    *(ushort4*)(ol + e) = l4;
}

// ---------------- rope cos/sin tables [j][l], j<32 ----------------
__launch_bounds__(256)
__global__ void rope_tab(float* __restrict__ tc, float* __restrict__ ts)
{
    const int idx = blockIdx.x*256 + threadIdx.x;   // 32*2048
    const int j = idx >> 11, l = idx & (NL-1);
    const float invf = 1.0f / powf(10000.0f, (float)j * (1.0f/32.0f));
    float s, c;
    sincosf((float)l * invf, &s, &c);
    tc[idx] = c; ts[idx] = s;
}

// ---------------- QKV GEMM: 128x128 tile, 2-slot dbuf (round-5/7 verified) ----------------
// 2-term hi/lo (ah*bh + al*bh), fused RoPE; Q (pre-scaled)/K bf16 -> [B,H,L,D],
// V -> transposed bf16 [B,H,D,L]. Pipeline: barrier -> stage(t+1) -> compute(t).
// LDS 50176 B (2x24K + guard, unions 36 KB V-bounce) -> 3 blocks/CU (grid = 3/CU).
__launch_bounds__(256, 3)
__global__ void gemm_qkv(const ushort_t* __restrict__ Ah, const ushort_t* __restrict__ Al,
                         const ushort_t* __restrict__ Bh,
                         const float* __restrict__ bias,
                         ushort_t* __restrict__ oQh, ushort_t* __restrict__ oKh,
                         ushort_t* __restrict__ oVth,
                         const float* __restrict__ tcos, const float* __restrict__ tsin)
{
    __shared__ __align__(16) char smem[50176];
    ushort_t* sA_h = (ushort_t*)smem;                    // 8 KB / slot
    ushort_t* sA_l = (ushort_t*)(smem + 8192);           // 8 KB / slot
    ushort_t* sB_h = (ushort_t*)(smem + 16384);          // 8 KB / slot
    ushort_t* sBounce = (ushort_t*)smem;                 // epilogue alias
    const int ebuf = 12288;                              // slot stride (elems)
    const int bbuf = 24576;                              // slot stride (bytes)

    const int tid  = threadIdx.x;
    const int wv   = tid >> 6, lane = tid & 63;
    const int quad = lane >> 4, l16 = lane & 15;
    const int m0 = blockIdx.y << 7, n0 = blockIdx.x << 7;
    const int wr = wv >> 1, wc = wv & 1;

    // staging: 0:A_h (8 passes) 1:A_l (8) 2:B_h rows0-63 (4) 3:B_h rows64-127 (4)
    const ushort_t* gsrc;
    ushort_t* lds_base;
    int rowb, npass;
    if (wv == 0)      { gsrc = Ah; lds_base = sA_h; rowb = m0; npass = 8; }
    else if (wv == 1) { gsrc = Al; lds_base = sA_l; rowb = m0; npass = 8; }
    else { gsrc = Bh; lds_base = sB_h + (wv-2)*64*32; rowb = n0 + (wv-2)*64; npass = 4; }
    const int rl = lane >> 2;
    const int cp = lane & 3;
    const int cg = cp ^ ((rl >> 1) & 3);
    const ushort_t* gptr = gsrc + (size_t)(rowb + rl)*NDIM + cg*8;

    f32x4 acc[4][4];
    #pragma unroll
    for (int i=0;i<4;++i)
        #pragma unroll
        for (int j=0;j<4;++j) acc[i][j] = (f32x4){0.f,0.f,0.f,0.f};

    const int swz = (l16 >> 1) & 3;
    const int ac_off = (wr*64 + l16)*32 + ((quad ^ swz) << 3);
    const int bc_off = (wc*64 + l16)*32 + ((quad ^ swz) << 3);

#define QSTAGE(BUF, KOFF) do { \
        const ushort_t* gp_ = gptr + (KOFF); \
        for (int p=0; p<npass; ++p) \
            async_load16(gp_ + (size_t)p*16*NDIM, (char*)lds_base + (BUF)*bbuf + p*1024); \
    } while(0)

#define QCOMP(BUF) do { \
        const int eo_ = (BUF)*ebuf; \
        short8 ah[4], al[4], bh[4]; \
        _Pragma("unroll") \
        for (int t=0;t<4;++t){ \
            ah[t] = *(const short8*)&sA_h[eo_ + t*512 + ac_off]; \
            al[t] = *(const short8*)&sA_l[eo_ + t*512 + ac_off]; \
            bh[t] = *(const short8*)&sB_h[eo_ + t*512 + bc_off]; \
        } \
        _Pragma("unroll") \
        for (int mt=0;mt<4;++mt) \
            _Pragma("unroll") \
            for (int nt=0;nt<4;++nt){ \
                f32x4 a_ = acc[mt][nt]; \
                a_ = MFMA16(ah[mt], bh[nt], a_); \
                a_ = MFMA16(al[mt], bh[nt], a_); \
                acc[mt][nt] = a_; \
            } \
    } while(0)

    QSTAGE(0, 0);
    for (int k0 = 0; k0 < NDIM; k0 += 64) {
        __syncthreads();                   // buf0 (k0) loads landed
        QSTAGE(1, k0 + 32);                // k0+32 <= 992 < NDIM always
        QCOMP(0);
        __syncthreads();                   // buf1 landed; buf0 free
        if (k0 + 64 < NDIM) QSTAGE(0, k0 + 64);
        QCOMP(1);
    }
#undef QSTAGE
#undef QCOMP

    const int colb = n0 + wc*64;          // 64-aligned -> single (sel, head)
    const int sel  = colb >> 10;          // 0:q 1:k 2:v
    const int head = (colb & 1023) >> 6;
    float bq[4];
    #pragma unroll
    for (int nt=0;nt<4;++nt) bq[nt] = bias[colb + nt*16 + l16];

    if (sel == 2) {
        // V -> transposed global [B,H,D,L] (bf16 only) via per-wave LDS bounce.
        // sBounce aliases the staging slots: barrier before overwrite.
        __syncthreads();
        const int bb = m0 >> 11;
        const int Lb = (m0 & (NL-1)) + wr*64;
        ushort_t* sT = sBounce + wv*(64*72);
        const size_t gb = ((size_t)(bb*NH + head)*ND)*NL + Lb;
        const int drow = lane >> 3, dcol = lane & 7;
        #pragma unroll
        for (int mt=0;mt<4;++mt)
            #pragma unroll
            for (int nt=0;nt<4;++nt)
                #pragma unroll
                for (int r=0;r<4;++r)
                    sT[(nt*16+l16)*72 + mt*16 + quad*4 + r] = f2bf(acc[mt][nt][r] + bq[nt]);
        #pragma unroll
        for (int dd=0; dd<8; ++dd){
            const int d = dd*8 + drow;
            const uint4 v = *(const uint4*)&sT[d*72 + dcol*8];
            *(uint4*)(oVth + gb + (size_t)d*NL + dcol*8) = v;
        }
    } else {
        ushort_t* dh = sel ? oKh : oQh;
        const float qs = sel ? 1.0f : QSCALE;
        #pragma unroll
        for (int mt=0;mt<4;++mt)
            #pragma unroll
            for (int r=0;r<4;++r){
                const int m = m0 + wr*64 + mt*16 + quad*4 + r;
                const int bb = m >> 11, l = m & (NL-1);
                const size_t ro = ((size_t)((bb*NH + head)*NL + l)) << 6;
                #pragma unroll
                for (int ntp=0;ntp<2;++ntp){
                    const int j = ntp*16 + l16;
                    const float c = tcos[j*NL + l];
                    const float s = tsin[j*NL + l];
                    const float x1 = acc[mt][ntp  ][r] + bq[ntp];
                    const float x2 = acc[mt][ntp+2][r] + bq[ntp+2];
                    const int d1 = ntp*16 + l16;
                    dh[ro + d1]      = f2bf((x1*c - x2*s) * qs);
                    dh[ro + d1 + 32] = f2bf((x2*c + x1*s) * qs);
                }
            }
    }
}

// ---------------- proj GEMM: 128x64 tile, 3-slot counted-vmcnt (round-7 verified) ----------------
// 3-term hi/lo, fp32 row-major C. Per phase: vmcnt(12) -> barrier -> COMP(slot)
// -> lgkmcnt(0) -> barrier (WAR) -> STAGE(slot, k+96). Every wave stages 6x1KB
// so the vmcnt literal is wave-uniform. Prefetch distance 3 phases (~900cy).
// LDS 74752 B -> 2 blocks/CU = grid density (512 blocks): zero occupancy cost.
__launch_bounds__(256, 2)
__global__ void gemm_proj(const ushort_t* __restrict__ Ah, const ushort_t* __restrict__ Al,
                          const ushort_t* __restrict__ Bh, const ushort_t* __restrict__ Bl,
                          const float* __restrict__ bias,
                          float* __restrict__ Cout)
{
    __shared__ __align__(16) char smem[74752];           // 3 x 24576 + 1024 pad
    ushort_t* sA_h = (ushort_t*)smem;                    // 8 KB / slot
    ushort_t* sA_l = (ushort_t*)(smem + 8192);           // 8 KB / slot
    ushort_t* sB_h = (ushort_t*)(smem + 16384);          // 4 KB / slot
    ushort_t* sB_l = (ushort_t*)(smem + 20480);          // 4 KB / slot
    const int ebuf = 12288;                              // slot stride (elems)
    const int bbuf = 24576;                              // slot stride (bytes)

    const int tid  = threadIdx.x;
    const int wv   = tid >> 6, lane = tid & 63;
    const int quad = lane >> 4, l16 = lane & 15;
    const int m0 = blockIdx.y << 7, n0 = blockIdx.x << 6;
    const int wr = wv >> 1, wc = wv & 1;

    // uniform staging: every wave 6 passes (A_h x2, A_l x2, B_h, B_l)
    const int rl = lane >> 2;
    const int cp = lane & 3;
    const int cg = cp ^ ((rl >> 1) & 3);
    const ushort_t* pAh = Ah + (size_t)(m0 + 32*wv + rl)*NDIM + cg*8;
    const ushort_t* pAl = Al + (size_t)(m0 + 32*wv + rl)*NDIM + cg*8;
    const ushort_t* pBh = Bh + (size_t)(n0 + 16*wv + rl)*NDIM + cg*8;
    const ushort_t* pBl = Bl + (size_t)(n0 + 16*wv + rl)*NDIM + cg*8;
    char* dA  = smem + wv*2048;                          // A_h; A_l at +8192
    char* dB0 = smem + 16384 + wv*1024;
    char* dB1 = smem + 20480 + wv*1024;

    f32x4 acc[4][2];
    #pragma unroll
    for (int i=0;i<4;++i)
        #pragma unroll
        for (int j=0;j<2;++j) acc[i][j] = (f32x4){0.f,0.f,0.f,0.f};

    const int swz = (l16 >> 1) & 3;
    const int ac_off = (wr*64 + l16)*32 + ((quad ^ swz) << 3);
    const int bc_off = (wc*32 + l16)*32 + ((quad ^ swz) << 3);

#define PSTAGE(SLOT, KOFF) do { \
        const int so_ = (SLOT)*bbuf; \
        async_load16(pAh + (KOFF),           dA + so_); \
        async_load16(pAh + 16*NDIM + (KOFF), dA + so_ + 1024); \
        async_load16(pAl + (KOFF),           dA + so_ + 8192); \
        async_load16(pAl + 16*NDIM + (KOFF), dA + so_ + 9216); \
        async_load16(pBh + (KOFF), dB0 + so_); \
        async_load16(pBl + (KOFF), dB1 + so_); \
    } while(0)

#define PCOMP(SLOT) do { \
        const int eo_ = (SLOT)*ebuf; \
        short8 ah[4], al[4], bh[2], bl[2]; \
        _Pragma("unroll") \
        for (int t=0;t<4;++t){ \
            ah[t] = *(const short8*)&sA_h[eo_ + t*512 + ac_off]; \
            al[t] = *(const short8*)&sA_l[eo_ + t*512 + ac_off]; \
        } \
        _Pragma("unroll") \
        for (int t=0;t<2;++t){ \
            bh[t] = *(const short8*)&sB_h[eo_ + t*512 + bc_off]; \
            bl[t] = *(const short8*)&sB_l[eo_ + t*512 + bc_off]; \
        } \
        _Pragma("unroll") \
        for (int mt=0;mt<4;++mt) \
            _Pragma("unroll") \
            for (int nt=0;nt<2;++nt){ \
                f32x4 a_ = acc[mt][nt]; \
                a_ = MFMA16(ah[mt], bh[nt], a_); \
                a_ = MFMA16(al[mt], bh[nt], a_); \
                a_ = MFMA16(ah[mt], bl[nt], a_); \
                acc[mt][nt] = a_; \
            } \
    } while(0)

#define PPHASE(SLOT, K0, VN) do { \
        asm volatile("s_waitcnt vmcnt(" #VN ")" ::: "memory"); \
        __builtin_amdgcn_sched_barrier(0); \
        __builtin_amdgcn_s_barrier(); \
        __builtin_amdgcn_sched_barrier(0); \
        PCOMP(SLOT); \
        asm volatile("s_waitcnt lgkmcnt(0)" ::: "memory"); \
        __builtin_amdgcn_sched_barrier(0); \
        __builtin_amdgcn_s_barrier(); \
        __builtin_amdgcn_sched_barrier(0); \
        if ((K0) + 96 < NDIM) PSTAGE(SLOT, (K0) + 96); \
    } while(0)

    PSTAGE(0, 0); PSTAGE(1, 32); PSTAGE(2, 64);
    for (int k0 = 0; k0 < 960; k0 += 96) {      // k = 0..928
        PPHASE(0, k0,      12);
        PPHASE(1, k0 + 32, 12);
        PPHASE(2, k0 + 64, 12);
    }
    PPHASE(0, 960, 0);                           // tail: full drain
    PPHASE(1, 992, 0);
#undef PSTAGE
#undef PCOMP
#undef PPHASE

    const int colb = n0 + wc*32;
    float bq[2];
    #pragma unroll
    for (int nt=0;nt<2;++nt) bq[nt] = bias[colb + nt*16 + l16];
    #pragma unroll
    for (int mt=0;mt<4;++mt)
        #pragma unroll
        for (int r=0;r<4;++r){
            const int m = m0 + wr*64 + mt*16 + quad*4 + r;
            float* orow = Cout + (size_t)m*NDIM + colb;
            #pragma unroll
            for (int nt=0;nt<2;++nt)
                orow[nt*16 + l16] = acc[mt][nt][r] + bq[nt];
        }
}

// ---------------- MFMA flash attention v3: 32 queries/wave, shared K/V frags ----------------
// block = 256 thr = 4 waves; each wave owns 32 queries (2 q-frags, round-0-verified
// mt layout) over ALL keys. K/V tiles staged into double-buffered LDS exactly as v2;
// K and V fragments are read from LDS ONCE per tile and reused for both q-frags
// (halves LDS traffic per query — v2 was LDS-BW-bound at ~37us floor, v3 ~20us).
// Softmax denominator via MFMA vs all-ones B frag, per q-frag.
__launch_bounds__(256, 3)
__global__ void attn_mfma(const ushort_t* __restrict__ Qh,
                          const ushort_t* __restrict__ Kh,
                          const ushort_t* __restrict__ Vth,
                          ushort_t* __restrict__ AOh, ushort_t* __restrict__ AOl,
                          const int* __restrict__ isg)
{
    // LDS map (bytes): [0,8K) K buf0 | [8K,16K) K buf1 | [16K,24K) V buf0
    //                  [24K,32K) V buf1 | [32K,48K) per-wave P tiles (4KB each)
    __shared__ __align__(16) char smem[49152];

    const int tid  = threadIdx.x;
    const int wv   = tid >> 6, lane = tid & 63;
    const int quad = lane >> 4, l16 = lane & 15;
    const int bh = blockIdx.x & 31, qt = blockIdx.x >> 5;   // qt 0..15 (128 q each)
    const int q0w = qt*128 + wv*32;

    // ---- Q B-frags (n=query on l16, k=d); Q pre-scaled by log2e/8 ----
    short8 bq[2][2];
    {
        const size_t rb = (((size_t)bh*NL + q0w) << 6);
        #pragma unroll
        for (int mt=0; mt<2; ++mt)
            #pragma unroll
            for (int c=0; c<2; ++c)
                bq[mt][c] = *(const short8*)(Qh + rb + (size_t)((mt*16 + l16) << 6) + quad*8 + c*32);
    }
    short8 ones;
    #pragma unroll
    for (int j=0;j<8;++j) ones[j] = (short)0x3F80;   // bf16 1.0

    f32x4 o[2][4];
    #pragma unroll
    for (int mt=0; mt<2; ++mt)
        #pragma unroll
        for (int dnt=0; dnt<4; ++dnt)
            o[mt][dnt] = (f32x4){0.f,0.f,0.f,0.f};
    f32x4 lsacc[2] = {(f32x4){0.f,0.f,0.f,0.f}, (f32x4){0.f,0.f,0.f,0.f}};

    const int gflag = isg[0];
    int klo, khi;
    if (gflag) { klo = 0; khi = NL; }
    else       { klo = (qt >> 1)*NWS; khi = klo + NWS; }   // qt covers 128 q; window 256 q

    // ---- LDS read/write lane constants (XOR swizzle: byte ^= (row&7)<<4) ----
    const int swz4 = (l16 & 7) << 4;
    const int KC0 = l16*128 + (( quad*16      ) ^ swz4);   // c=0 frag (k 0-31)
    const int KC1 = l16*128 + (( quad*16 + 64 ) ^ swz4);   // c=1 frag (k 32-63)
    const int sPb = 32768 + wv*4096;                       // 32 rows x 128 B per wave
    int PW[4];
    #pragma unroll
    for (int knt=0; knt<4; ++knt)
        PW[knt] = sPb + l16*128 + ((knt*32 + quad*8) ^ swz4);   // + mt*2048
    const int PR0 = sPb + KC0;                                  // + mt*2048
    const int PR1 = sPb + KC1;

    // ---- staging pointers: pre-swizzled global source, linear LDS dest ----
    // wave wv stages rows [wv*16, wv*16+16) of both the K tile and the V^T tile
    const int r8  = lane >> 3;
    const int c8s = (lane & 7) ^ r8;                       // swizzled 16B slot
    const ushort_t* Kp = Kh + (((size_t)bh*NL) << 6)
                       + (size_t)(klo + wv*16 + r8)*64 + c8s*8;
    const ushort_t* Vp = Vth + (size_t)bh*ND*NL
                       + (size_t)(wv*16 + r8)*NL + klo + c8s*8;
    const int kdst = wv*2048;            // + BUF*8192
    const int vdst = 16384 + wv*2048;    // + BUF*8192

#define STAGE(BUF) do { \
        async_load16(Kp,          smem + (BUF)*8192 + kdst); \
        async_load16(Kp + 512,    smem + (BUF)*8192 + kdst + 1024); \
        async_load16(Vp,          smem + (BUF)*8192 + vdst); \
        async_load16(Vp + 8*NL,   smem + (BUF)*8192 + vdst + 1024); \
        Kp += 64*64; Vp += 64; } while (0)

#define TILE(BUF) do { \
        const char* kb_ = smem + (BUF)*8192; \
        const char* vb_ = smem + 16384 + (BUF)*8192; \
        f32x4 s0_[4], s1_[4]; \
        _Pragma("unroll") \
        for (int knt=0; knt<4; ++knt) { \
            const short8 a0 = *(const short8*)(kb_ + knt*2048 + KC0); \
            const short8 a1 = *(const short8*)(kb_ + knt*2048 + KC1); \
            f32x4 t0 = (f32x4){0.f,0.f,0.f,0.f}; \
            t0 = MFMA16(a0, bq[0][0], t0); \
            t0 = MFMA16(a1, bq[0][1], t0); \
            s0_[knt] = t0; \
            f32x4 t1 = (f32x4){0.f,0.f,0.f,0.f}; \
            t1 = MFMA16(a0, bq[1][0], t1); \
            t1 = MFMA16(a1, bq[1][1], t1); \
            s1_[knt] = t1; \
        } \
        short8 fp[2][2]; \
        _Pragma("unroll") \
        for (int mt=0; mt<2; ++mt) { \
            _Pragma("unroll") \
            for (int knt=0; knt<4; ++knt) { \
                const f32x4 sv = mt ? s1_[knt] : s0_[knt]; \
                const uint_t u0 = __float_as_uint(fast_exp2(sv[0])); \
                const uint_t u1 = __float_as_uint(fast_exp2(sv[1])); \
                const uint_t u2 = __float_as_uint(fast_exp2(sv[2])); \
                const uint_t u3 = __float_as_uint(fast_exp2(sv[3])); \
                uint2 pk_; \
                pk_.x = __builtin_amdgcn_perm(u1, u0, 0x07060302u); \
                pk_.y = __builtin_amdgcn_perm(u3, u2, 0x07060302u); \
                *(uint2*)(smem + mt*2048 + PW[knt]) = pk_; \
            } \
            fp[mt][0] = *(const short8*)(smem + mt*2048 + PR0); \
            fp[mt][1] = *(const short8*)(smem + mt*2048 + PR1); \
            lsacc[mt] = MFMA16(fp[mt][0], ones, lsacc[mt]); \
            lsacc[mt] = MFMA16(fp[mt][1], ones, lsacc[mt]); \
        } \
        _Pragma("unroll") \
        for (int dnt=0; dnt<4; ++dnt) { \
            const short8 v0 = *(const short8*)(vb_ + dnt*2048 + KC0); \
            const short8 v1 = *(const short8*)(vb_ + dnt*2048 + KC1); \
            _Pragma("unroll") \
            for (int mt=0; mt<2; ++mt) { \
                f32x4 t = o[mt][dnt]; \
                t = MFMA16(fp[mt][0], v0, t); \
                t = MFMA16(fp[mt][1], v1, t); \
                o[mt][dnt] = t; \
            } \
        } } while (0)

    STAGE(0);
    for (int kt = klo; kt < khi; kt += 128) {
        __syncthreads();                       // drains vmcnt: tile kt landed
        if (kt + 64 < khi) STAGE(1);
        TILE(0);
        __syncthreads();                       // tile kt+64 landed
        if (kt + 128 < khi) STAGE(0);
        TILE(1);
    }
#undef STAGE
#undef TILE

    // ---- epilogue: O rows = mt*16 + quad*4 + r; lsacc in matching layout ----
    const int bb = bh >> 4, hh = bh & 15;
    #pragma unroll
    for (int mt=0; mt<2; ++mt)
        #pragma unroll
        for (int r=0; r<4; ++r) {
            const float inv = 1.0f / lsacc[mt][r];
            const int row = q0w + mt*16 + quad*4 + r;
            const size_t ob = (((size_t)(bb*NL + row)) << 10) + (hh << 6);
            #pragma unroll
            for (int dnt=0; dnt<4; ++dnt) {
                const float val = o[mt][dnt][r] * inv;
                const ushort_t h = f2bf(val);
                AOh[ob + dnt*16 + l16] = h;
                AOl[ob + dnt*16 + l16] = f2bf(val - bf2f(h));
            }
        }
}

extern "C" void kernel_launch(void* const* d_in, const int* in_sizes, int n_in,
                              void* d_out, int out_size, void* d_ws, size_t ws_size,
                              hipStream_t stream)
{
    const float* x     = (const float*)d_in[0];
    const float* Wqkv  = (const float*)d_in[1];
    const float* bqkv  = (const float*)d_in[2];
    const float* Wproj = (const float*)d_in[3];
    const float* bproj = (const float*)d_in[4];
    const int*   isg   = (const int*)d_in[5];
    float* out = (float*)d_out;
    char* base = (char*)d_ws;

    const size_t MB = 1024*1024;
    ushort_t* Qh  = (ushort_t*)(base);
    ushort_t* Kh  = (ushort_t*)(base + 16*MB);
    ushort_t* Vth = (ushort_t*)(base + 32*MB);
    ushort_t* xh  = (ushort_t*)(base + 48*MB);
    ushort_t* xl  = (ushort_t*)(base + 56*MB);
    ushort_t* AOh = xh;                       // alias: xh dead after gemm1
    ushort_t* AOl = xl;
    ushort_t* Wqh = (ushort_t*)(base + 64*MB);
    ushort_t* Wql = (ushort_t*)(base + 64*MB + 6291456);
    ushort_t* Wph = (ushort_t*)(base + 76*MB);
    ushort_t* Wpl = (ushort_t*)(base + 76*MB + 2097152);
    float*    tcs = (float*)(base + 80*MB);          // 32*2048 f32
    float*    tsn = (float*)(base + 80*MB + 262144);

    split_all<<<8192, 256, 0, stream>>>(x, xh, xl, Wqkv, Wqh, Wql, Wproj, Wph, Wpl);
    rope_tab<<<256, 256, 0, stream>>>(tcs, tsn);

    gemm_qkv<<<dim3(3*NDIM/128, NM/128), 256, 0, stream>>>(
        xh, xl, Wqh, bqkv, Qh, Kh, Vth, tcs, tsn);

    attn_mfma<<<NB*NH*(NL/128), 256, 0, stream>>>(
        Qh, Kh, Vth, AOh, AOl, isg);

    gemm_proj<<<dim3(NDIM/64, NM/128), 256, 0, stream>>>(
        AOh, AOl, Wph, Wpl, bproj, out);
}